// Round 1
// baseline (4283.062 us; speedup 1.0000x reference)
//
#include <hip/hip_runtime.h>
#include <math.h>

#define N 96
#define NN (N * N)
#define MPM_ITERS 50

// ws layout (floats):
// [0      ,  9216) W      : W[a*N+b] = B[a,b]*dB^2 (0 on diag), symmetric
// [9216   , 18432) ns     : node_block[i,a] = sig1 / (|degA[i]-degB[a]|+1)
// [18432  , 18528) degA
// [18528  , 18624) degB
// [18624  , 27840) Y0
// [27840  , 37056) Y1
// total 37056 floats = 148224 bytes

__global__ void k_setup1(const float* __restrict__ A, const float* __restrict__ vec,
                         float* __restrict__ W, float* __restrict__ degA,
                         float* __restrict__ degB) {
    int r = blockIdx.x;
    int t = threadIdx.x;
    __shared__ float redB[128];
    __shared__ float redA[128];
    float b_rc = 0.f, a_rc = 0.f;
    if (t < N) {
        int c = t;
        float logit;
        if (c == r) {
            logit = 1.0f;
        } else {
            int i = (r < c) ? r : c;
            int j = (r < c) ? c : r;
            int idx = i * (N - 1) - (i * (i - 1)) / 2 + (j - i - 1);
            logit = vec[idx];
        }
        b_rc = 1.0f / (1.0f + expf(-logit));
        a_rc = A[r * N + c];
    }
    redB[t] = b_rc;
    redA[t] = a_rc;
    __syncthreads();
    for (int s = 64; s >= 1; s >>= 1) {
        if (t < s) { redB[t] += redB[t + s]; redA[t] += redA[t + s]; }
        __syncthreads();
    }
    if (t == 0) { degB[r] = redB[0]; degA[r] = redA[0]; }
    if (t < N) {
        const float s1 = 1.0f / (1.0f + expf(-1.0f));  // dB (diag of B)
        float w = (t == r) ? 0.0f : b_rc * s1 * s1;
        W[r * N + t] = w;
    }
}

__global__ void k_setup2(const float* __restrict__ degA, const float* __restrict__ degB,
                         float* __restrict__ nsb, float* __restrict__ Y0) {
    int r = blockIdx.x;
    int t = threadIdx.x;
    if (t < N) {
        const float s1 = 1.0f / (1.0f + expf(-1.0f));
        nsb[r * N + t] = s1 / (fabsf(degA[r] - degB[t]) + 1.0f);
        Y0[r * N + t] = 1.0f / 96.0f;
    }
}

// One MPM step: Yn = f(Yp / ||Yp||)   (f is positively homogeneous, so we
// apply the scale once at the end). Norm of Yp is recomputed redundantly per
// block with a fixed tree -> deterministic, no atomics, no extra launch.
__global__ void k_iter(const float* __restrict__ A, const float* __restrict__ W,
                       const float* __restrict__ nsb, const float* __restrict__ Yp,
                       float* __restrict__ Yn) {
    int i = blockIdx.x;
    int t = threadIdx.x;
    __shared__ float red[128];
    float s = 0.f;
    for (int e = t; e < NN; e += 128) {
        float v = Yp[e];
        s = fmaf(v, v, s);
    }
    red[t] = s;
    __syncthreads();
    for (int st = 64; st >= 1; st >>= 1) {
        if (t < st) red[t] += red[t + st];
        __syncthreads();
    }
    float norm = sqrtf(red[0]);

    if (t < N) {
        int a = t;
        float acc = Yp[i * N + a] * nsb[i * N + a];
        for (int j = 0; j < N; ++j) {
            if (j == i) continue;
            if (A[i * N + j] > 0.5f) {
                // M[j,a] = max_b W[a,b]*Yp[j,b]; W symmetric -> read W[b*N+a]
                // (coalesced across lanes a). 4 independent max chains for ILP.
                float m0 = 0.f, m1 = 0.f, m2 = 0.f, m3 = 0.f;
                const float* Wc = W + a;
                const float* xr = Yp + j * N;
#pragma unroll
                for (int b = 0; b < N; b += 4) {
                    m0 = fmaxf(m0, Wc[(b + 0) * N] * xr[b + 0]);
                    m1 = fmaxf(m1, Wc[(b + 1) * N] * xr[b + 1]);
                    m2 = fmaxf(m2, Wc[(b + 2) * N] * xr[b + 2]);
                    m3 = fmaxf(m3, Wc[(b + 3) * N] * xr[b + 3]);
                }
                acc += fmaxf(fmaxf(m0, m1), fmaxf(m2, m3));
            }
        }
        Yn[i * N + a] = acc / norm;
    }
}

__global__ void k_final(const float* __restrict__ Y, float* __restrict__ out) {
    int i = blockIdx.x;
    int t = threadIdx.x;
    __shared__ float red[128];
    float s = 0.f;
    for (int e = t; e < NN; e += 128) {
        float v = Y[e];
        s = fmaf(v, v, s);
    }
    red[t] = s;
    __syncthreads();
    for (int st = 64; st >= 1; st >>= 1) {
        if (t < st) red[t] += red[t + st];
        __syncthreads();
    }
    float norm = sqrtf(red[0]);
    if (t < N) out[i * N + t] = Y[i * N + t] / norm;
}

extern "C" void kernel_launch(void* const* d_in, const int* in_sizes, int n_in,
                              void* d_out, int out_size, void* d_ws, size_t ws_size,
                              hipStream_t stream) {
    const float* A = (const float*)d_in[0];     // A_gt, 96*96
    const float* vec = (const float*)d_in[1];   // vec_logits, 4560
    float* ws = (float*)d_ws;
    float* W    = ws;
    float* nsb  = ws + 9216;
    float* degA = ws + 18432;
    float* degB = ws + 18528;
    float* Y0   = ws + 18624;
    float* Y1   = ws + 27840;
    float* out  = (float*)d_out;

    k_setup1<<<96, 128, 0, stream>>>(A, vec, W, degA, degB);
    k_setup2<<<96, 128, 0, stream>>>(degA, degB, nsb, Y0);

    float* yp = Y0;
    float* yn = Y1;
    for (int k = 0; k < MPM_ITERS; ++k) {
        k_iter<<<96, 128, 0, stream>>>(A, W, nsb, yp, yn);
        float* tmp = yp; yp = yn; yn = tmp;
    }
    k_final<<<96, 128, 0, stream>>>(yp, out);
}

// Round 2
// 989.297 us; speedup vs baseline: 4.3294x; 4.3294x over previous
//
#include <hip/hip_runtime.h>
#include <math.h>

#define N 96
#define T 768          // 12 waves
#define GJ 8           // thread group count: thread handles rows j ≡ g (mod 8)
#define ITERS 50

// One fused kernel: setup + 50 MPM iterations + output, single workgroup.
// Per thread: column a = t%96, group g = t/96.
//   - Wreg[96]  : W[:,a] = B[:,a]*sigmoid(1)^2 (diag 0) held in VGPRs
//   - M phase   : M[j,a] = max_b Wreg[b]*X[j,b] for its 12 rows (2 halves of 6)
//   - agg phase : y[i,a] = X[i,a]*ns[i,a] + sum_{j in nbr(i)} M[j,a], i = g+8k
//   - norm      : block reduction, X = y / ||y||
__global__ __launch_bounds__(T, 1) void k_fused(const float* __restrict__ A,
                                                const float* __restrict__ vec,
                                                float* __restrict__ out) {
    __shared__ float Xs[N * N];            // 36864 B : X (also staging for B, then A)
    __shared__ float Mh[48 * N];           // 18432 B : M for one j-half
    __shared__ unsigned char lst[N * 48];  //  4608 B : neighbor lists (ascending j)
    __shared__ short cnt[N];
    __shared__ short cntlo[N];             // neighbors with j < 48
    __shared__ float degA[N];
    __shared__ float degB[N];
    __shared__ float red[T / 64];
    __shared__ float snorm;

    const int t = threadIdx.x;
    const int a = t % N;
    const int g = t / N;
    const float s1 = 1.0f / (1.0f + expf(-1.0f));   // sigmoid(1) = diag of B
    const float s1s1 = s1 * s1;

    // ---- setup phase 0: B -> Xs (staging) ----
#pragma unroll
    for (int k = 0; k < 12; ++k) {
        int e = t + k * T;
        int r = e / N, c = e % N;
        float logit;
        if (r == c) {
            logit = 1.0f;
        } else {
            int i = r < c ? r : c;
            int j = r < c ? c : r;
            int idx = i * 95 - (i * (i - 1)) / 2 + (j - i - 1);
            logit = vec[idx];
        }
        Xs[e] = 1.0f / (1.0f + expf(-logit));
    }
    __syncthreads();

    // W column into registers (B symmetric: col a == row a), zero diagonal
    float Wreg[96];
#pragma unroll
    for (int b = 0; b < N; ++b)
        Wreg[b] = (b == a) ? 0.0f : Xs[b * N + a] * s1s1;

    // degB: column sums of B (lanes read consecutive addresses, conflict-free)
    if (t < N) {
        float s = 0.f;
        for (int r = 0; r < N; ++r) s += Xs[r * N + t];
        degB[t] = s;
    }
    __syncthreads();   // all reads of B done

    // ---- setup phase 1: A -> Xs (staging) ----
#pragma unroll
    for (int k = 0; k < 12; ++k) {
        int e = t + k * T;
        Xs[e] = A[e];
    }
    __syncthreads();

    if (t < N) {
        float s = 0.f;
        for (int r = 0; r < N; ++r) s += Xs[r * N + t];   // A symmetric
        degA[t] = s;
    } else if (t < 2 * N) {
        int i = t - N;
        int c_ = 0, clo = 0;
        for (int j = 0; j < N; ++j) {
            if (j == 48) clo = c_;
            if (j != i && Xs[j * N + i] > 0.5f)            // A symmetric
                lst[i * 48 + c_++] = (unsigned char)j;
        }
        cnt[i] = (short)c_;
        cntlo[i] = (short)clo;
    }
    __syncthreads();   // lists/degs ready, Xs(A) reads done

    // node-sim coefficients for this thread's 12 output entries (i = g+8k, a)
    float ns_reg[12];
#pragma unroll
    for (int k = 0; k < 12; ++k) {
        int i = g + GJ * k;
        ns_reg[k] = s1 / (fabsf(degA[i] - degB[a]) + 1.0f);
    }

    // X0 = 1/96 everywhere (||X0|| = 1 exactly, matching the reference)
#pragma unroll
    for (int k = 0; k < 12; ++k) Xs[t + k * T] = (1.0f / 96.0f);
    __syncthreads();

    // ---- main loop ----
    float y[12];
    for (int it = 0; it < ITERS; ++it) {
        // diag term first (same summation order as the previously-exact kernel)
#pragma unroll
        for (int k = 0; k < 12; ++k)
            y[k] = Xs[(g + GJ * k) * N + a] * ns_reg[k];

        for (int h = 0; h < 2; ++h) {
            // M for rows j in [48h, 48h+48) with j ≡ g (mod 8): 6 rows
#pragma unroll
            for (int jj = 0; jj < 6; ++jj) {
                int jl = jj * GJ + g;             // row index within half
                const float* xr = &Xs[(48 * h + jl) * N];
                float m0 = 0.f, m1 = 0.f, m2 = 0.f, m3 = 0.f;
#pragma unroll
                for (int b = 0; b < N; b += 4) {
                    float4 x = *(const float4*)(xr + b);   // broadcast ds_read_b128
                    m0 = fmaxf(m0, Wreg[b + 0] * x.x);
                    m1 = fmaxf(m1, Wreg[b + 1] * x.y);
                    m2 = fmaxf(m2, Wreg[b + 2] * x.z);
                    m3 = fmaxf(m3, Wreg[b + 3] * x.w);
                }
                Mh[jl * N + a] = fmaxf(fmaxf(m0, m1), fmaxf(m2, m3));
            }
            __syncthreads();   // Mh ready

            // aggregate this half's neighbors (ascending j order preserved)
#pragma unroll
            for (int k = 0; k < 12; ++k) {
                int i = g + GJ * k;
                int q0 = h ? (int)cntlo[i] : 0;
                int q1 = h ? (int)cnt[i] : (int)cntlo[i];
                float acc = y[k];
                for (int q = q0; q < q1; ++q) {
                    int j = (int)lst[i * 48 + q];
                    acc += Mh[(j - 48 * h) * N + a];
                }
                y[k] = acc;
            }
            __syncthreads();   // agg reads done before Mh is rewritten
        }

        // block-wide norm of y
        float ss = 0.f;
#pragma unroll
        for (int k = 0; k < 12; ++k) ss = fmaf(y[k], y[k], ss);
#pragma unroll
        for (int m = 1; m < 64; m <<= 1) ss += __shfl_xor(ss, m, 64);
        if ((t & 63) == 0) red[t >> 6] = ss;
        __syncthreads();
        if (t == 0) {
            float s = 0.f;
#pragma unroll
            for (int w = 0; w < T / 64; ++w) s += red[w];
            snorm = 1.0f / sqrtf(s);
        }
        __syncthreads();
        float inv = snorm;
#pragma unroll
        for (int k = 0; k < 12; ++k)
            Xs[(g + GJ * k) * N + a] = y[k] * inv;
        __syncthreads();
    }

    // ---- output ----
#pragma unroll
    for (int k = 0; k < 12; ++k) {
        int e = t + k * T;
        out[e] = Xs[e];
    }
}

extern "C" void kernel_launch(void* const* d_in, const int* in_sizes, int n_in,
                              void* d_out, int out_size, void* d_ws, size_t ws_size,
                              hipStream_t stream) {
    const float* A = (const float*)d_in[0];     // A_gt, 96*96
    const float* vec = (const float*)d_in[1];   // vec_logits, 4560
    float* out = (float*)d_out;
    k_fused<<<1, T, 0, stream>>>(A, vec, out);
}